// Round 5
// baseline (288.096 us; speedup 1.0000x reference)
//
#include <hip/hip_runtime.h>
#include <hip/hip_bf16.h>

#define DM 256
#define NH 8
#define HD 32
#define NLV 3
#define NPT 4
#define NLP 12
#define BB 16
#define LQ 300
#define NT 8400
#define MROWS (BB * NT)      // 134400
#define QROWS (BB * LQ)      // 4800
#define KP 40                // padded LDS K-stride for BK=32 kernels
#define KP2 72               // padded LDS K-stride for BK=64 kernel (valproj)

typedef __bf16 bf16x8 __attribute__((ext_vector_type(8)));
typedef __bf16 bf16x4 __attribute__((ext_vector_type(4)));
typedef float  f32x16 __attribute__((ext_vector_type(16)));

// ---------------------------------------------------------------------------
// Kernel 0: pre-transpose + pre-tile weights to bf16.
// blocks 0..255   -> Wt  [ktile(8)][n(256)][k(32)]  from W_val
// blocks 256..543 -> Wt2 [ktile(8)][n(288)][k(32)]  from [W_off | W_attn]
// blocks 544..799 -> Wt3 [ktile(8)][n(256)][k(32)]  from W_out
// ---------------------------------------------------------------------------
__global__ void k_wt(const float* __restrict__ W_val,
                     const float* __restrict__ W_off,
                     const float* __restrict__ W_attn,
                     const float* __restrict__ W_out,
                     __hip_bfloat16* __restrict__ Wt,
                     __hip_bfloat16* __restrict__ Wt2,
                     __hip_bfloat16* __restrict__ Wt3)
{
    const int n = blockIdx.x;
    const int k = threadIdx.x;
    if (n < 256) {
        Wt[(size_t)(k >> 5) * 8192 + n * 32 + (k & 31)] =
            __float2bfloat16(W_val[(size_t)k * 256 + n]);
    } else if (n < 544) {
        const int n2 = n - 256;   // 0..287
        float v = (n2 < 192) ? W_off[(size_t)k * 192 + n2]
                             : W_attn[(size_t)k * 96 + (n2 - 192)];
        Wt2[(size_t)(k >> 5) * 9216 + n2 * 32 + (k & 31)] = __float2bfloat16(v);
    } else {
        const int n3 = n - 544;   // 0..255
        Wt3[(size_t)(k >> 5) * 8192 + n3 * 32 + (k & 31)] =
            __float2bfloat16(W_out[(size_t)k * 256 + n3]);
    }
}

// ---------------------------------------------------------------------------
// Kernel 1: value = input_flatten @ W_val + b_val (bf16 MFMA), permuted store
// to (b, h, pos, d) bf16.
// Round-5 shape: BM=32, BN=256, BK=64, 256 thr = 4 waves; wave = 32m x 64n
// (2 acc tiles = 32 AGPR).  Single LDS buffer, 4 K-iterations.
// Rationale: round-4 dbuf was neutral; 64-AGPR acc capped occupancy at
// 2 waves/SIMD.  Halve acc + halve serial rounds -> 4 waves/SIMD.
// ---------------------------------------------------------------------------
__global__ __launch_bounds__(256) void k_valproj(
    const float* __restrict__ A,             // (134400, 256) fp32
    const __hip_bfloat16* __restrict__ Wt,   // tiled bf16 W^T
    const float* __restrict__ bias,          // (256,)
    __hip_bfloat16* __restrict__ V)          // (16, 8, 8400, 32)
{
    __shared__ __hip_bfloat16 As[32 * KP2];    //  4,608 B
    __shared__ __hip_bfloat16 Ws[256 * KP2];   // 36,864 B

    const int t    = threadIdx.x;
    const int m0   = blockIdx.x * 32;
    const int wave = t >> 6;
    const int lane = t & 63;
    const int lm   = lane & 31;
    const int lk   = (lane >> 5) * 8;

    f32x16 acc[2];
#pragma unroll
    for (int j = 0; j < 2; j++)
#pragma unroll
        for (int e = 0; e < 16; e++) acc[j][e] = 0.f;

    const int ar = t >> 3;          // A row 0..31
    const int ak = (t & 7) * 8;     // A k-chunk 0..56

    for (int kt = 0; kt < 256; kt += 64) {
        // ---- stage A tile (32 x 64) fp32 -> bf16: 8 elems/thread ----
        {
            const float* ap = A + (size_t)(m0 + ar) * 256 + kt + ak;
            float4 a0 = *(const float4*)ap;
            float4 a1 = *(const float4*)(ap + 4);
            union { __hip_bfloat162 h2[4]; bf16x8 v; } ua;
            ua.h2[0] = __float22bfloat162_rn(make_float2(a0.x, a0.y));
            ua.h2[1] = __float22bfloat162_rn(make_float2(a0.z, a0.w));
            ua.h2[2] = __float22bfloat162_rn(make_float2(a1.x, a1.y));
            ua.h2[3] = __float22bfloat162_rn(make_float2(a1.z, a1.w));
            *(bf16x8*)(As + ar * KP2 + ak) = ua.v;
        }
        // ---- stage W tile (256 n x 64 k): thread t = row n, 2 k-chunks ----
        {
            const int kt5 = kt >> 5;
            const __hip_bfloat16* wp0 = Wt + (size_t)kt5 * 8192 + t * 32;
            const __hip_bfloat16* wp1 = wp0 + 8192;
            __hip_bfloat16* wd = Ws + t * KP2;
            *(bf16x8*)(wd + 0)  = *(const bf16x8*)(wp0 + 0);
            *(bf16x8*)(wd + 8)  = *(const bf16x8*)(wp0 + 8);
            *(bf16x8*)(wd + 16) = *(const bf16x8*)(wp0 + 16);
            *(bf16x8*)(wd + 24) = *(const bf16x8*)(wp0 + 24);
            *(bf16x8*)(wd + 32) = *(const bf16x8*)(wp1 + 0);
            *(bf16x8*)(wd + 40) = *(const bf16x8*)(wp1 + 8);
            *(bf16x8*)(wd + 48) = *(const bf16x8*)(wp1 + 16);
            *(bf16x8*)(wd + 56) = *(const bf16x8*)(wp1 + 24);
        }
        __syncthreads();

#pragma unroll
        for (int kk = 0; kk < 64; kk += 16) {
            bf16x8 af  = *(const bf16x8*)(As + lm * KP2 + kk + lk);
            bf16x8 bf0 = *(const bf16x8*)(Ws + (wave * 64 + lm) * KP2 + kk + lk);
            bf16x8 bf1 = *(const bf16x8*)(Ws + (wave * 64 + 32 + lm) * KP2 + kk + lk);
            acc[0] = __builtin_amdgcn_mfma_f32_32x32x16_bf16(af, bf0, acc[0], 0, 0, 0);
            acc[1] = __builtin_amdgcn_mfma_f32_32x32x16_bf16(af, bf1, acc[1], 0, 0, 0);
        }
        __syncthreads();
    }

    // ---- epilogue: bias + bf16 + permuted store (b, h, pos, d) ----
#pragma unroll
    for (int j = 0; j < 2; j++) {
        const int n  = wave * 64 + j * 32 + lm;
        const float bn = bias[n];
        const int h  = n >> 5;
        const int d  = n & 31;
#pragma unroll
        for (int r = 0; r < 16; r++) {
            int rl = (r & 3) + 8 * (r >> 2) + 4 * (lane >> 5);
            int m  = m0 + rl;
            int b  = m / NT;
            int pos = m - b * NT;
            V[((size_t)(b * NH + h) * NT + pos) * HD + d] =
                __float2bfloat16(acc[j][r] + bn);
        }
    }
}

// ---------------------------------------------------------------------------
// Kernel 2 (MFMA): [off_raw | attn_raw] = query @ [W_off | W_attn] + bias.
// ---------------------------------------------------------------------------
__global__ __launch_bounds__(192) void k_offattn(
    const float* __restrict__ Q,             // (4800, 256)
    const __hip_bfloat16* __restrict__ Wt2,  // tiled bf16 [W_off|W_attn]^T
    const float* __restrict__ boff,          // (192,)
    const float* __restrict__ battn,         // (96,)
    float* __restrict__ off_out,             // (4800, 192)
    float* __restrict__ attn_out)            // (4800, 96)
{
    __shared__ __hip_bfloat16 As[32 * KP];
    __shared__ __hip_bfloat16 Ws[288 * KP];

    const int t    = threadIdx.x;
    const int m0   = blockIdx.x * 32;
    const int wave = t >> 6;       // 0..2
    const int lane = t & 63;
    const int lm   = lane & 31;
    const int lk   = (lane >> 5) * 8;

    f32x16 acc[3];
#pragma unroll
    for (int j = 0; j < 3; j++)
#pragma unroll
        for (int e = 0; e < 16; e++) acc[j][e] = 0.f;

    for (int kt = 0; kt < 256; kt += 32) {
        if (t < 128) {
            const int ar = t >> 2;
            const int ak = (t & 3) * 8;
            const float* ap = Q + (size_t)(m0 + ar) * 256 + kt + ak;
            float4 a0 = *(const float4*)ap;
            float4 a1 = *(const float4*)(ap + 4);
            union { __hip_bfloat162 h2[4]; bf16x8 v; } ua;
            ua.h2[0] = __float22bfloat162_rn(make_float2(a0.x, a0.y));
            ua.h2[1] = __float22bfloat162_rn(make_float2(a0.z, a0.w));
            ua.h2[2] = __float22bfloat162_rn(make_float2(a1.x, a1.y));
            ua.h2[3] = __float22bfloat162_rn(make_float2(a1.z, a1.w));
            *(bf16x8*)(As + ar * KP + ak) = ua.v;
        }
        {
            const __hip_bfloat16* wp = Wt2 + (size_t)(kt >> 5) * 9216 + t * 32;
            __hip_bfloat16* wd = Ws + t * KP;
            *(bf16x8*)(wd + 0)  = *(const bf16x8*)(wp + 0);
            *(bf16x8*)(wd + 8)  = *(const bf16x8*)(wp + 8);
            *(bf16x8*)(wd + 16) = *(const bf16x8*)(wp + 16);
            *(bf16x8*)(wd + 24) = *(const bf16x8*)(wp + 24);
            if (t < 96) {
                const __hip_bfloat16* wp2 = Wt2 + (size_t)(kt >> 5) * 9216 + (t + 192) * 32;
                __hip_bfloat16* wd2 = Ws + (t + 192) * KP;
                *(bf16x8*)(wd2 + 0)  = *(const bf16x8*)(wp2 + 0);
                *(bf16x8*)(wd2 + 8)  = *(const bf16x8*)(wp2 + 8);
                *(bf16x8*)(wd2 + 16) = *(const bf16x8*)(wp2 + 16);
                *(bf16x8*)(wd2 + 24) = *(const bf16x8*)(wp2 + 24);
            }
        }
        __syncthreads();

#pragma unroll
        for (int kk = 0; kk < 32; kk += 16) {
            bf16x8 af = *(const bf16x8*)(As + lm * KP + kk + lk);
#pragma unroll
            for (int j = 0; j < 3; j++) {
                bf16x8 bf = *(const bf16x8*)(Ws + (wave * 96 + j * 32 + lm) * KP + kk + lk);
                acc[j] = __builtin_amdgcn_mfma_f32_32x32x16_bf16(af, bf, acc[j], 0, 0, 0);
            }
        }
        __syncthreads();
    }

#pragma unroll
    for (int j = 0; j < 3; j++) {
        const int n = wave * 96 + j * 32 + lm;
        const float bias_ = (n < 192) ? boff[n] : battn[n - 192];
#pragma unroll
        for (int r = 0; r < 16; r++) {
            int rl = (r & 3) + 8 * (r >> 2) + 4 * (lane >> 5);
            int m  = m0 + rl;
            float v = acc[j][r] + bias_;
            if (n < 192) off_out[(size_t)m * 192 + n] = v;
            else         attn_out[(size_t)m * 96 + (n - 192)] = v;
        }
    }
}

// ---------------------------------------------------------------------------
// Kernel 3: softmax + sampling.  2 queries per block (256 thr = 2 x 128).
// ---------------------------------------------------------------------------
__global__ __launch_bounds__(256) void k_sample(
    const float* __restrict__ off_raw,   // (4800, 192)  (h,l,p,2)
    const float* __restrict__ attn_raw,  // (4800, 96)   (h, l*4+p)
    const float* __restrict__ refp,      // (16, 300, 3, 2)
    const __hip_bfloat16* __restrict__ V,// (16, 8, 8400, 32)
    __hip_bfloat16* __restrict__ sampled)// (4800, 256) bf16
{
    const int t  = threadIdx.x;
    const int q2 = t >> 7;          // 0..1
    const int tq = t & 127;
    const int bq = blockIdx.x * 2 + q2;
    const int b  = bq / LQ;

    __shared__ float aw[2][96];
    __shared__ float wc[2][96][4];
    __shared__ int   ic[2][96][4];

    if (tq < 8) {
        float v[12];
        float mx = -1e30f;
#pragma unroll
        for (int i = 0; i < 12; i++) {
            v[i] = attn_raw[(size_t)bq * 96 + tq * 12 + i];
            mx = fmaxf(mx, v[i]);
        }
        float s = 0.f;
#pragma unroll
        for (int i = 0; i < 12; i++) { v[i] = expf(v[i] - mx); s += v[i]; }
        float inv = 1.f / s;
#pragma unroll
        for (int i = 0; i < 12; i++) aw[q2][tq * 12 + i] = v[i] * inv;
    }
    __syncthreads();

    if (tq < 96) {
        const float dims[3]  = {80.f, 40.f, 20.f};
        const int startsl[3] = {0, 6400, 8000};
        const int idiml[3]   = {80, 40, 20};
        int h = tq / 12, lp = tq - h * 12, l = lp >> 2, p = lp & 3;
        float ox = off_raw[(size_t)bq * 192 + ((h * 3 + l) * 4 + p) * 2 + 0];
        float oy = off_raw[(size_t)bq * 192 + ((h * 3 + l) * 4 + p) * 2 + 1];
        float rx = refp[(size_t)bq * 6 + l * 2 + 0];
        float ry = refp[(size_t)bq * 6 + l * 2 + 1];
        float D  = dims[l];
        float lx = rx + ox / D;
        float ly = ry + oy / D;
        float ix = lx * D - 0.5f;
        float iy = ly * D - 0.5f;
        const int Dl = idiml[l];
        const int st = startsl[l];

        float fix = floorf(ix), fiy = floorf(iy);
        int ix0 = (int)fix, iy0 = (int)fiy;
        int ix1 = ix0 + 1, iy1 = iy0 + 1;
        float fx = ix - fix, fy = iy - fiy;

        float mx0 = (ix0 >= 0 && ix0 < Dl) ? 1.f : 0.f;
        float mx1 = (ix1 >= 0 && ix1 < Dl) ? 1.f : 0.f;
        float my0 = (iy0 >= 0 && iy0 < Dl) ? 1.f : 0.f;
        float my1 = (iy1 >= 0 && iy1 < Dl) ? 1.f : 0.f;

        int cx0 = min(max(ix0, 0), Dl - 1);
        int cx1 = min(max(ix1, 0), Dl - 1);
        int cy0 = min(max(iy0, 0), Dl - 1);
        int cy1 = min(max(iy1, 0), Dl - 1);

        float a = aw[q2][tq];
        wc[q2][tq][0] = (1.f - fx) * (1.f - fy) * mx0 * my0 * a;
        wc[q2][tq][1] = fx * (1.f - fy) * mx1 * my0 * a;
        wc[q2][tq][2] = (1.f - fx) * fy * mx0 * my1 * a;
        wc[q2][tq][3] = fx * fy * mx1 * my1 * a;
        ic[q2][tq][0] = (st + cy0 * Dl + cx0) * HD;
        ic[q2][tq][1] = (st + cy0 * Dl + cx1) * HD;
        ic[q2][tq][2] = (st + cy1 * Dl + cx0) * HD;
        ic[q2][tq][3] = (st + cy1 * Dl + cx1) * HD;
    }
    __syncthreads();

    const int h  = tq >> 4;
    const int dp = (tq & 15) * 2;
    const __hip_bfloat16* vb = V + (size_t)(b * NH + h) * NT * HD + dp;

    float acc0 = 0.f, acc1 = 0.f;
#pragma unroll
    for (int lp = 0; lp < 12; lp++) {
        const int s = h * 12 + lp;
        float4 w4 = *(const float4*)(&wc[q2][s][0]);
        int4   i4 = *(const int4*)(&ic[q2][s][0]);
        float2 v00 = __bfloat1622float2(*(const __hip_bfloat162*)(vb + i4.x));
        float2 v01 = __bfloat1622float2(*(const __hip_bfloat162*)(vb + i4.y));
        float2 v10 = __bfloat1622float2(*(const __hip_bfloat162*)(vb + i4.z));
        float2 v11 = __bfloat1622float2(*(const __hip_bfloat162*)(vb + i4.w));
        acc0 = fmaf(w4.x, v00.x, fmaf(w4.y, v01.x, fmaf(w4.z, v10.x, fmaf(w4.w, v11.x, acc0))));
        acc1 = fmaf(w4.x, v00.y, fmaf(w4.y, v01.y, fmaf(w4.z, v10.y, fmaf(w4.w, v11.y, acc1))));
    }
    *(__hip_bfloat162*)(sampled + (size_t)bq * 256 + h * 32 + dp) =
        __float22bfloat162_rn(make_float2(acc0, acc1));
}

// ---------------------------------------------------------------------------
// Kernel 4 (MFMA): out = sampled(bf16) @ W_out + b_out.
// ---------------------------------------------------------------------------
__global__ __launch_bounds__(256) void k_outproj(
    const __hip_bfloat16* __restrict__ A,    // (4800, 256) bf16
    const __hip_bfloat16* __restrict__ Wt3,  // tiled bf16 W_out^T
    const float* __restrict__ bias,          // (256,)
    float* __restrict__ out)                 // (4800, 256)
{
    __shared__ __hip_bfloat16 As[32 * KP];
    __shared__ __hip_bfloat16 Ws[256 * KP];

    const int t    = threadIdx.x;
    const int m0   = blockIdx.x * 32;
    const int wave = t >> 6;       // 0..3
    const int lane = t & 63;
    const int lm   = lane & 31;
    const int lk   = (lane >> 5) * 8;

    f32x16 acc[2];
#pragma unroll
    for (int j = 0; j < 2; j++)
#pragma unroll
        for (int e = 0; e < 16; e++) acc[j][e] = 0.f;

    const int ar = t >> 3;         // 0..31
    const int ak = (t & 7) * 4;    // 0..28

    for (int kt = 0; kt < 256; kt += 32) {
        *(bf16x4*)(As + ar * KP + ak) =
            *(const bf16x4*)(A + (size_t)(m0 + ar) * 256 + kt + ak);
        {
            const __hip_bfloat16* wp = Wt3 + (size_t)(kt >> 5) * 8192 + t * 32;
            __hip_bfloat16* wd = Ws + t * KP;
            *(bf16x8*)(wd + 0)  = *(const bf16x8*)(wp + 0);
            *(bf16x8*)(wd + 8)  = *(const bf16x8*)(wp + 8);
            *(bf16x8*)(wd + 16) = *(const bf16x8*)(wp + 16);
            *(bf16x8*)(wd + 24) = *(const bf16x8*)(wp + 24);
        }
        __syncthreads();

#pragma unroll
        for (int kk = 0; kk < 32; kk += 16) {
            bf16x8 af = *(const bf16x8*)(As + lm * KP + kk + lk);
            bf16x8 bf0 = *(const bf16x8*)(Ws + (wave * 64 + 0 * 32 + lm) * KP + kk + lk);
            bf16x8 bf1 = *(const bf16x8*)(Ws + (wave * 64 + 1 * 32 + lm) * KP + kk + lk);
            acc[0] = __builtin_amdgcn_mfma_f32_32x32x16_bf16(af, bf0, acc[0], 0, 0, 0);
            acc[1] = __builtin_amdgcn_mfma_f32_32x32x16_bf16(af, bf1, acc[1], 0, 0, 0);
        }
        __syncthreads();
    }

#pragma unroll
    for (int j = 0; j < 2; j++) {
        const int n = wave * 64 + j * 32 + lm;
        const float bn = bias[n];
#pragma unroll
        for (int r = 0; r < 16; r++) {
            int rl = (r & 3) + 8 * (r >> 2) + 4 * (lane >> 5);
            int m  = m0 + rl;
            out[(size_t)m * 256 + n] = acc[j][r] + bn;
        }
    }
}

// ---------------------------------------------------------------------------
extern "C" void kernel_launch(void* const* d_in, const int* in_sizes, int n_in,
                              void* d_out, int out_size, void* d_ws, size_t ws_size,
                              hipStream_t stream) {
    const float* query  = (const float*)d_in[0];
    const float* refp   = (const float*)d_in[1];
    const float* inputf = (const float*)d_in[2];
    const float* W_off  = (const float*)d_in[3];
    const float* b_off  = (const float*)d_in[4];
    const float* W_attn = (const float*)d_in[5];
    const float* b_attn = (const float*)d_in[6];
    const float* W_val  = (const float*)d_in[7];
    const float* b_val  = (const float*)d_in[8];
    const float* W_out  = (const float*)d_in[9];
    const float* b_out  = (const float*)d_in[10];
    float* out = (float*)d_out;

    char* ws = (char*)d_ws;
    __hip_bfloat16* value   = (__hip_bfloat16*)ws;                       // 68,812,800
    float* off_raw          = (float*)(ws + 68812800);                   //  3,686,400
    float* attn_raw         = (float*)(ws + 72499200);                   //  1,843,200
    __hip_bfloat16* sampled = (__hip_bfloat16*)(ws + 74342400);          //  2,457,600
    __hip_bfloat16* Wt      = (__hip_bfloat16*)(ws + 76800000);          //    131,072
    __hip_bfloat16* Wt2     = (__hip_bfloat16*)(ws + 76931072);          //    147,456
    __hip_bfloat16* Wt3     = (__hip_bfloat16*)(ws + 77078528);          //    131,072

    k_wt<<<800, 256, 0, stream>>>(W_val, W_off, W_attn, W_out, Wt, Wt2, Wt3);
    k_valproj<<<MROWS / 32, 256, 0, stream>>>(inputf, Wt, b_val, value);
    k_offattn<<<QROWS / 32, 192, 0, stream>>>(query, Wt2, b_off, b_attn,
                                              off_raw, attn_raw);
    k_sample<<<QROWS / 2, 256, 0, stream>>>(off_raw, attn_raw, refp, value, sampled);
    k_outproj<<<QROWS / 32, 256, 0, stream>>>(sampled, Wt3, b_out, out);
}

// Round 6
// 279.214 us; speedup vs baseline: 1.0318x; 1.0318x over previous
//
#include <hip/hip_runtime.h>
#include <hip/hip_bf16.h>

#define DM 256
#define NH 8
#define HD 32
#define NLV 3
#define NPT 4
#define NLP 12
#define BB 16
#define LQ 300
#define NT 8400
#define MROWS (BB * NT)      // 134400
#define QROWS (BB * LQ)      // 4800
#define KP 40                // padded LDS K-stride for BK=32 kernels
#define KP2 72               // padded LDS K-stride for valproj A tile (BK=64)

typedef __bf16 bf16x8 __attribute__((ext_vector_type(8)));
typedef __bf16 bf16x4 __attribute__((ext_vector_type(4)));
typedef float  f32x16 __attribute__((ext_vector_type(16)));

// ---------------------------------------------------------------------------
// Kernel 0: pre-tile weights to bf16.
// blocks 0..255   -> Wf  fragment-major from W_val:
//                    Wf[(k>>3)*2048 + n*8 + (k&7)] = W_val[k][n]
//                    (lane fragment = 16 B contiguous; consecutive n -> coalesced)
// blocks 256..543 -> Wt2 [ktile(8)][n(288)][k(32)]  from [W_off | W_attn]
// blocks 544..799 -> Wt3 [ktile(8)][n(256)][k(32)]  from W_out
// ---------------------------------------------------------------------------
__global__ void k_wt(const float* __restrict__ W_val,
                     const float* __restrict__ W_off,
                     const float* __restrict__ W_attn,
                     const float* __restrict__ W_out,
                     __hip_bfloat16* __restrict__ Wf,
                     __hip_bfloat16* __restrict__ Wt2,
                     __hip_bfloat16* __restrict__ Wt3)
{
    const int n = blockIdx.x;
    const int k = threadIdx.x;
    if (n < 256) {
        Wf[(size_t)(k >> 3) * 2048 + n * 8 + (k & 7)] =
            __float2bfloat16(W_val[(size_t)k * 256 + n]);
    } else if (n < 544) {
        const int n2 = n - 256;   // 0..287
        float v = (n2 < 192) ? W_off[(size_t)k * 192 + n2]
                             : W_attn[(size_t)k * 96 + (n2 - 192)];
        Wt2[(size_t)(k >> 5) * 9216 + n2 * 32 + (k & 31)] = __float2bfloat16(v);
    } else {
        const int n3 = n - 544;   // 0..255
        Wt3[(size_t)(k >> 5) * 8192 + n3 * 32 + (k & 31)] =
            __float2bfloat16(W_out[(size_t)k * 256 + n3]);
    }
}

// ---------------------------------------------------------------------------
// Kernel 1: value = input_flatten @ W_val + b_val (bf16 MFMA), permuted store.
// Round-6: W fragments loaded DIRECTLY from global (fragment-major Wf,
// L2-resident, no LDS, no barrier dependency -> loads stay in flight across
// the barrier).  Only A goes through LDS (fp32->bf16), double-buffered,
// ONE barrier per K-iteration.  BM=32, BN=256, BK=64, 4 waves.
// ---------------------------------------------------------------------------
__global__ __launch_bounds__(256) void k_valproj(
    const float* __restrict__ A,             // (134400, 256) fp32
    const __hip_bfloat16* __restrict__ Wf,   // fragment-major bf16 W
    const float* __restrict__ bias,          // (256,)
    __hip_bfloat16* __restrict__ V)          // (16, 8, 8400, 32)
{
    __shared__ __hip_bfloat16 As[2][32 * KP2];   // 2 x 4.5 KB

    const int t    = threadIdx.x;
    const int m0   = blockIdx.x * 32;
    const int wave = t >> 6;
    const int lane = t & 63;
    const int lm   = lane & 31;
    const int kh   = lane >> 5;      // k-half within 16-step
    const int lk   = kh * 8;

    f32x16 acc[2];
#pragma unroll
    for (int j = 0; j < 2; j++)
#pragma unroll
        for (int e = 0; e < 16; e++) acc[j][e] = 0.f;

    const int ar = t >> 3;          // A row 0..31
    const int ak = (t & 7) * 8;     // A k-chunk 0..56

    // lane-invariant W fragment base: n0 = wave*64 + lm, k-half kh.
    // frag(g, j) at wf0 + g*4096 + j*256   (elems), g = global k / 16
    const __hip_bfloat16* wf0 = Wf + (size_t)(wave * 64 + lm) * 8 + kh * 2048;

    // prologue: stage A k-tile 0 into buf 0
    {
        const float* ap = A + (size_t)(m0 + ar) * 256 + ak;
        float4 a0 = *(const float4*)ap;
        float4 a1 = *(const float4*)(ap + 4);
        union { __hip_bfloat162 h2[4]; bf16x8 v; } ua;
        ua.h2[0] = __float22bfloat162_rn(make_float2(a0.x, a0.y));
        ua.h2[1] = __float22bfloat162_rn(make_float2(a0.z, a0.w));
        ua.h2[2] = __float22bfloat162_rn(make_float2(a1.x, a1.y));
        ua.h2[3] = __float22bfloat162_rn(make_float2(a1.z, a1.w));
        *(bf16x8*)(&As[0][ar * KP2 + ak]) = ua.v;
    }
    __syncthreads();

#pragma unroll
    for (int it = 0; it < 4; ++it) {
        const int buf = it & 1;
        // prefetch next A k-tile into registers (overlaps with MFMA below)
        float4 na0, na1;
        if (it < 3) {
            const float* ap = A + (size_t)(m0 + ar) * 256 + (it + 1) * 64 + ak;
            na0 = *(const float4*)ap;
            na1 = *(const float4*)(ap + 4);
        }
        // 4 k-steps of 16; W fragments direct from global (L2)
#pragma unroll
        for (int ks = 0; ks < 4; ++ks) {
            const int g = it * 4 + ks;
            bf16x8 af = *(const bf16x8*)(&As[buf][lm * KP2 + ks * 16 + lk]);
            bf16x8 b0 = *(const bf16x8*)(wf0 + (size_t)g * 4096);
            bf16x8 b1 = *(const bf16x8*)(wf0 + (size_t)g * 4096 + 256);
            acc[0] = __builtin_amdgcn_mfma_f32_32x32x16_bf16(af, b0, acc[0], 0, 0, 0);
            acc[1] = __builtin_amdgcn_mfma_f32_32x32x16_bf16(af, b1, acc[1], 0, 0, 0);
        }
        // stage prefetched A into the other buffer; single barrier per iter
        if (it < 3) {
            union { __hip_bfloat162 h2[4]; bf16x8 v; } ua;
            ua.h2[0] = __float22bfloat162_rn(make_float2(na0.x, na0.y));
            ua.h2[1] = __float22bfloat162_rn(make_float2(na0.z, na0.w));
            ua.h2[2] = __float22bfloat162_rn(make_float2(na1.x, na1.y));
            ua.h2[3] = __float22bfloat162_rn(make_float2(na1.z, na1.w));
            *(bf16x8*)(&As[buf ^ 1][ar * KP2 + ak]) = ua.v;
            __syncthreads();
        }
    }

    // ---- epilogue: bias + bf16 + permuted store (b, h, pos, d) ----
#pragma unroll
    for (int j = 0; j < 2; j++) {
        const int n  = wave * 64 + j * 32 + lm;
        const float bn = bias[n];
        const int h  = n >> 5;
        const int d  = n & 31;
#pragma unroll
        for (int r = 0; r < 16; r++) {
            int rl = (r & 3) + 8 * (r >> 2) + 4 * kh;
            int m  = m0 + rl;
            int b  = m / NT;
            int pos = m - b * NT;
            V[((size_t)(b * NH + h) * NT + pos) * HD + d] =
                __float2bfloat16(acc[j][r] + bn);
        }
    }
}

// ---------------------------------------------------------------------------
// Kernel 2 (MFMA): [off_raw | attn_raw] = query @ [W_off | W_attn] + bias.
// ---------------------------------------------------------------------------
__global__ __launch_bounds__(192) void k_offattn(
    const float* __restrict__ Q,             // (4800, 256)
    const __hip_bfloat16* __restrict__ Wt2,  // tiled bf16 [W_off|W_attn]^T
    const float* __restrict__ boff,          // (192,)
    const float* __restrict__ battn,         // (96,)
    float* __restrict__ off_out,             // (4800, 192)
    float* __restrict__ attn_out)            // (4800, 96)
{
    __shared__ __hip_bfloat16 As[32 * KP];
    __shared__ __hip_bfloat16 Ws[288 * KP];

    const int t    = threadIdx.x;
    const int m0   = blockIdx.x * 32;
    const int wave = t >> 6;       // 0..2
    const int lane = t & 63;
    const int lm   = lane & 31;
    const int lk   = (lane >> 5) * 8;

    f32x16 acc[3];
#pragma unroll
    for (int j = 0; j < 3; j++)
#pragma unroll
        for (int e = 0; e < 16; e++) acc[j][e] = 0.f;

    for (int kt = 0; kt < 256; kt += 32) {
        if (t < 128) {
            const int ar = t >> 2;
            const int ak = (t & 3) * 8;
            const float* ap = Q + (size_t)(m0 + ar) * 256 + kt + ak;
            float4 a0 = *(const float4*)ap;
            float4 a1 = *(const float4*)(ap + 4);
            union { __hip_bfloat162 h2[4]; bf16x8 v; } ua;
            ua.h2[0] = __float22bfloat162_rn(make_float2(a0.x, a0.y));
            ua.h2[1] = __float22bfloat162_rn(make_float2(a0.z, a0.w));
            ua.h2[2] = __float22bfloat162_rn(make_float2(a1.x, a1.y));
            ua.h2[3] = __float22bfloat162_rn(make_float2(a1.z, a1.w));
            *(bf16x8*)(As + ar * KP + ak) = ua.v;
        }
        {
            const __hip_bfloat16* wp = Wt2 + (size_t)(kt >> 5) * 9216 + t * 32;
            __hip_bfloat16* wd = Ws + t * KP;
            *(bf16x8*)(wd + 0)  = *(const bf16x8*)(wp + 0);
            *(bf16x8*)(wd + 8)  = *(const bf16x8*)(wp + 8);
            *(bf16x8*)(wd + 16) = *(const bf16x8*)(wp + 16);
            *(bf16x8*)(wd + 24) = *(const bf16x8*)(wp + 24);
            if (t < 96) {
                const __hip_bfloat16* wp2 = Wt2 + (size_t)(kt >> 5) * 9216 + (t + 192) * 32;
                __hip_bfloat16* wd2 = Ws + (t + 192) * KP;
                *(bf16x8*)(wd2 + 0)  = *(const bf16x8*)(wp2 + 0);
                *(bf16x8*)(wd2 + 8)  = *(const bf16x8*)(wp2 + 8);
                *(bf16x8*)(wd2 + 16) = *(const bf16x8*)(wp2 + 16);
                *(bf16x8*)(wd2 + 24) = *(const bf16x8*)(wp2 + 24);
            }
        }
        __syncthreads();

#pragma unroll
        for (int kk = 0; kk < 32; kk += 16) {
            bf16x8 af = *(const bf16x8*)(As + lm * KP + kk + lk);
#pragma unroll
            for (int j = 0; j < 3; j++) {
                bf16x8 bf = *(const bf16x8*)(Ws + (wave * 96 + j * 32 + lm) * KP + kk + lk);
                acc[j] = __builtin_amdgcn_mfma_f32_32x32x16_bf16(af, bf, acc[j], 0, 0, 0);
            }
        }
        __syncthreads();
    }

#pragma unroll
    for (int j = 0; j < 3; j++) {
        const int n = wave * 96 + j * 32 + lm;
        const float bias_ = (n < 192) ? boff[n] : battn[n - 192];
#pragma unroll
        for (int r = 0; r < 16; r++) {
            int rl = (r & 3) + 8 * (r >> 2) + 4 * (lane >> 5);
            int m  = m0 + rl;
            float v = acc[j][r] + bias_;
            if (n < 192) off_out[(size_t)m * 192 + n] = v;
            else         attn_out[(size_t)m * 96 + (n - 192)] = v;
        }
    }
}

// ---------------------------------------------------------------------------
// Kernel 3: softmax + sampling.  2 queries per block (256 thr = 2 x 128).
// ---------------------------------------------------------------------------
__global__ __launch_bounds__(256) void k_sample(
    const float* __restrict__ off_raw,   // (4800, 192)  (h,l,p,2)
    const float* __restrict__ attn_raw,  // (4800, 96)   (h, l*4+p)
    const float* __restrict__ refp,      // (16, 300, 3, 2)
    const __hip_bfloat16* __restrict__ V,// (16, 8, 8400, 32)
    __hip_bfloat16* __restrict__ sampled)// (4800, 256) bf16
{
    const int t  = threadIdx.x;
    const int q2 = t >> 7;          // 0..1
    const int tq = t & 127;
    const int bq = blockIdx.x * 2 + q2;
    const int b  = bq / LQ;

    __shared__ float aw[2][96];
    __shared__ float wc[2][96][4];
    __shared__ int   ic[2][96][4];

    if (tq < 8) {
        float v[12];
        float mx = -1e30f;
#pragma unroll
        for (int i = 0; i < 12; i++) {
            v[i] = attn_raw[(size_t)bq * 96 + tq * 12 + i];
            mx = fmaxf(mx, v[i]);
        }
        float s = 0.f;
#pragma unroll
        for (int i = 0; i < 12; i++) { v[i] = expf(v[i] - mx); s += v[i]; }
        float inv = 1.f / s;
#pragma unroll
        for (int i = 0; i < 12; i++) aw[q2][tq * 12 + i] = v[i] * inv;
    }
    __syncthreads();

    if (tq < 96) {
        const float dims[3]  = {80.f, 40.f, 20.f};
        const int startsl[3] = {0, 6400, 8000};
        const int idiml[3]   = {80, 40, 20};
        int h = tq / 12, lp = tq - h * 12, l = lp >> 2, p = lp & 3;
        float ox = off_raw[(size_t)bq * 192 + ((h * 3 + l) * 4 + p) * 2 + 0];
        float oy = off_raw[(size_t)bq * 192 + ((h * 3 + l) * 4 + p) * 2 + 1];
        float rx = refp[(size_t)bq * 6 + l * 2 + 0];
        float ry = refp[(size_t)bq * 6 + l * 2 + 1];
        float D  = dims[l];
        float lx = rx + ox / D;
        float ly = ry + oy / D;
        float ix = lx * D - 0.5f;
        float iy = ly * D - 0.5f;
        const int Dl = idiml[l];
        const int st = startsl[l];

        float fix = floorf(ix), fiy = floorf(iy);
        int ix0 = (int)fix, iy0 = (int)fiy;
        int ix1 = ix0 + 1, iy1 = iy0 + 1;
        float fx = ix - fix, fy = iy - fiy;

        float mx0 = (ix0 >= 0 && ix0 < Dl) ? 1.f : 0.f;
        float mx1 = (ix1 >= 0 && ix1 < Dl) ? 1.f : 0.f;
        float my0 = (iy0 >= 0 && iy0 < Dl) ? 1.f : 0.f;
        float my1 = (iy1 >= 0 && iy1 < Dl) ? 1.f : 0.f;

        int cx0 = min(max(ix0, 0), Dl - 1);
        int cx1 = min(max(ix1, 0), Dl - 1);
        int cy0 = min(max(iy0, 0), Dl - 1);
        int cy1 = min(max(iy1, 0), Dl - 1);

        float a = aw[q2][tq];
        wc[q2][tq][0] = (1.f - fx) * (1.f - fy) * mx0 * my0 * a;
        wc[q2][tq][1] = fx * (1.f - fy) * mx1 * my0 * a;
        wc[q2][tq][2] = (1.f - fx) * fy * mx0 * my1 * a;
        wc[q2][tq][3] = fx * fy * mx1 * my1 * a;
        ic[q2][tq][0] = (st + cy0 * Dl + cx0) * HD;
        ic[q2][tq][1] = (st + cy0 * Dl + cx1) * HD;
        ic[q2][tq][2] = (st + cy1 * Dl + cx0) * HD;
        ic[q2][tq][3] = (st + cy1 * Dl + cx1) * HD;
    }
    __syncthreads();

    const int h  = tq >> 4;
    const int dp = (tq & 15) * 2;
    const __hip_bfloat16* vb = V + (size_t)(b * NH + h) * NT * HD + dp;

    float acc0 = 0.f, acc1 = 0.f;
#pragma unroll
    for (int lp = 0; lp < 12; lp++) {
        const int s = h * 12 + lp;
        float4 w4 = *(const float4*)(&wc[q2][s][0]);
        int4   i4 = *(const int4*)(&ic[q2][s][0]);
        float2 v00 = __bfloat1622float2(*(const __hip_bfloat162*)(vb + i4.x));
        float2 v01 = __bfloat1622float2(*(const __hip_bfloat162*)(vb + i4.y));
        float2 v10 = __bfloat1622float2(*(const __hip_bfloat162*)(vb + i4.z));
        float2 v11 = __bfloat1622float2(*(const __hip_bfloat162*)(vb + i4.w));
        acc0 = fmaf(w4.x, v00.x, fmaf(w4.y, v01.x, fmaf(w4.z, v10.x, fmaf(w4.w, v11.x, acc0))));
        acc1 = fmaf(w4.x, v00.y, fmaf(w4.y, v01.y, fmaf(w4.z, v10.y, fmaf(w4.w, v11.y, acc1))));
    }
    *(__hip_bfloat162*)(sampled + (size_t)bq * 256 + h * 32 + dp) =
        __float22bfloat162_rn(make_float2(acc0, acc1));
}

// ---------------------------------------------------------------------------
// Kernel 4 (MFMA): out = sampled(bf16) @ W_out + b_out.
// ---------------------------------------------------------------------------
__global__ __launch_bounds__(256) void k_outproj(
    const __hip_bfloat16* __restrict__ A,    // (4800, 256) bf16
    const __hip_bfloat16* __restrict__ Wt3,  // tiled bf16 W_out^T
    const float* __restrict__ bias,          // (256,)
    float* __restrict__ out)                 // (4800, 256)
{
    __shared__ __hip_bfloat16 As[32 * KP];
    __shared__ __hip_bfloat16 Ws[256 * KP];

    const int t    = threadIdx.x;
    const int m0   = blockIdx.x * 32;
    const int wave = t >> 6;       // 0..3
    const int lane = t & 63;
    const int lm   = lane & 31;
    const int lk   = (lane >> 5) * 8;

    f32x16 acc[2];
#pragma unroll
    for (int j = 0; j < 2; j++)
#pragma unroll
        for (int e = 0; e < 16; e++) acc[j][e] = 0.f;

    const int ar = t >> 3;         // 0..31
    const int ak = (t & 7) * 4;    // 0..28

    for (int kt = 0; kt < 256; kt += 32) {
        *(bf16x4*)(As + ar * KP + ak) =
            *(const bf16x4*)(A + (size_t)(m0 + ar) * 256 + kt + ak);
        {
            const __hip_bfloat16* wp = Wt3 + (size_t)(kt >> 5) * 8192 + t * 32;
            __hip_bfloat16* wd = Ws + t * KP;
            *(bf16x8*)(wd + 0)  = *(const bf16x8*)(wp + 0);
            *(bf16x8*)(wd + 8)  = *(const bf16x8*)(wp + 8);
            *(bf16x8*)(wd + 16) = *(const bf16x8*)(wp + 16);
            *(bf16x8*)(wd + 24) = *(const bf16x8*)(wp + 24);
        }
        __syncthreads();

#pragma unroll
        for (int kk = 0; kk < 32; kk += 16) {
            bf16x8 af = *(const bf16x8*)(As + lm * KP + kk + lk);
            bf16x8 bf0 = *(const bf16x8*)(Ws + (wave * 64 + 0 * 32 + lm) * KP + kk + lk);
            bf16x8 bf1 = *(const bf16x8*)(Ws + (wave * 64 + 1 * 32 + lm) * KP + kk + lk);
            acc[0] = __builtin_amdgcn_mfma_f32_32x32x16_bf16(af, bf0, acc[0], 0, 0, 0);
            acc[1] = __builtin_amdgcn_mfma_f32_32x32x16_bf16(af, bf1, acc[1], 0, 0, 0);
        }
        __syncthreads();
    }

#pragma unroll
    for (int j = 0; j < 2; j++) {
        const int n = wave * 64 + j * 32 + lm;
        const float bn = bias[n];
#pragma unroll
        for (int r = 0; r < 16; r++) {
            int rl = (r & 3) + 8 * (r >> 2) + 4 * (lane >> 5);
            int m  = m0 + rl;
            out[(size_t)m * 256 + n] = acc[j][r] + bn;
        }
    }
}

// ---------------------------------------------------------------------------
extern "C" void kernel_launch(void* const* d_in, const int* in_sizes, int n_in,
                              void* d_out, int out_size, void* d_ws, size_t ws_size,
                              hipStream_t stream) {
    const float* query  = (const float*)d_in[0];
    const float* refp   = (const float*)d_in[1];
    const float* inputf = (const float*)d_in[2];
    const float* W_off  = (const float*)d_in[3];
    const float* b_off  = (const float*)d_in[4];
    const float* W_attn = (const float*)d_in[5];
    const float* b_attn = (const float*)d_in[6];
    const float* W_val  = (const float*)d_in[7];
    const float* b_val  = (const float*)d_in[8];
    const float* W_out  = (const float*)d_in[9];
    const float* b_out  = (const float*)d_in[10];
    float* out = (float*)d_out;

    char* ws = (char*)d_ws;
    __hip_bfloat16* value   = (__hip_bfloat16*)ws;                       // 68,812,800
    float* off_raw          = (float*)(ws + 68812800);                   //  3,686,400
    float* attn_raw         = (float*)(ws + 72499200);                   //  1,843,200
    __hip_bfloat16* sampled = (__hip_bfloat16*)(ws + 74342400);          //  2,457,600
    __hip_bfloat16* Wf      = (__hip_bfloat16*)(ws + 76800000);          //    131,072
    __hip_bfloat16* Wt2     = (__hip_bfloat16*)(ws + 76931072);          //    147,456
    __hip_bfloat16* Wt3     = (__hip_bfloat16*)(ws + 77078528);          //    131,072

    k_wt<<<800, 256, 0, stream>>>(W_val, W_off, W_attn, W_out, Wf, Wt2, Wt3);
    k_valproj<<<MROWS / 32, 256, 0, stream>>>(inputf, Wf, b_val, value);
    k_offattn<<<QROWS / 32, 192, 0, stream>>>(query, Wt2, b_off, b_attn,
                                              off_raw, attn_raw);
    k_sample<<<QROWS / 2, 256, 0, stream>>>(off_raw, attn_raw, refp, value, sampled);
    k_outproj<<<QROWS / 32, 256, 0, stream>>>(sampled, Wt3, b_out, out);
}